// Round 3
// baseline (825.624 us; speedup 1.0000x reference)
//
#include <hip/hip_runtime.h>
#include <hip/hip_bf16.h>
#include <math.h>

#define NQ 8192
#define DD 256
#define NHD 8
#define HDD 32
#define PP 25
#define HH 512
#define WW 512
#define HWSZ (HH * WW)
#define DFF 1024

typedef __bf16 bf16_t;
typedef bf16_t bf16x8 __attribute__((ext_vector_type(8)));
typedef bf16_t bf16x4 __attribute__((ext_vector_type(4)));
typedef float f32x4 __attribute__((ext_vector_type(4)));

// ---------------------------------------------------------------------------
// Streaming Wv projection: V(HW,256) = bf16( memory(HW,256)fp32 @ Wv^T + bv )
// W held entirely in registers (wave owns 64-col slice: 4 j-tiles x 8 k-tiles
// bf16x8 = 128 VGPR). A streamed global->VGPR (16 float4/lane per 16-row
// chunk), fp32->bf16 inline, 32 MFMAs/chunk. No LDS, no barriers.
// Block = 4 waves (cover N=256), 16 chunks (256 rows) per block.
// ---------------------------------------------------------------------------
__global__ __launch_bounds__(256, 2) void wv_kernel(
    const float* __restrict__ A, const bf16_t* __restrict__ Wt,
    const float* __restrict__ bias, __hip_bfloat16* __restrict__ V) {
  const int tid = threadIdx.x;
  const int wave = tid >> 6;
  const int lane = tid & 63;
  const int l15 = lane & 15;
  const int quad = lane >> 4;
  const int wslice = wave * 64;
  const int base = blockIdx.x * 256;

  // B fragments: frag[n=l15][k=quad*8..+7] per (j,kt) tile
  bf16x8 bfr[4][8];
#pragma unroll
  for (int j = 0; j < 4; j++) {
    const bf16_t* wp = Wt + (size_t)(wslice + j * 16 + l15) * 256 + quad * 8;
#pragma unroll
    for (int kt = 0; kt < 8; kt++) bfr[j][kt] = *(const bf16x8*)(wp + kt * 32);
  }
  float bsv[4];
#pragma unroll
  for (int j = 0; j < 4; j++) bsv[j] = bias[wslice + j * 16 + l15];

  for (int c = 0; c < 16; c++) {
    const int m0 = base + c * 16;
    const float* ap = A + (size_t)(m0 + l15) * 256 + quad * 8;
    float4 av[8][2];
#pragma unroll
    for (int kt = 0; kt < 8; kt++) {
      av[kt][0] = *(const float4*)(ap + kt * 32);
      av[kt][1] = *(const float4*)(ap + kt * 32 + 4);
    }
    f32x4 acc[4];
#pragma unroll
    for (int j = 0; j < 4; j++) acc[j] = (f32x4){0.f, 0.f, 0.f, 0.f};
#pragma unroll
    for (int kt = 0; kt < 8; kt++) {
      bf16x8 afr;
      afr[0] = (bf16_t)av[kt][0].x;
      afr[1] = (bf16_t)av[kt][0].y;
      afr[2] = (bf16_t)av[kt][0].z;
      afr[3] = (bf16_t)av[kt][0].w;
      afr[4] = (bf16_t)av[kt][1].x;
      afr[5] = (bf16_t)av[kt][1].y;
      afr[6] = (bf16_t)av[kt][1].z;
      afr[7] = (bf16_t)av[kt][1].w;
#pragma unroll
      for (int j = 0; j < 4; j++)
        acc[j] = __builtin_amdgcn_mfma_f32_16x16x32_bf16(afr, bfr[j][kt],
                                                         acc[j], 0, 0, 0);
    }
#pragma unroll
    for (int j = 0; j < 4; j++) {
      const int col = wslice + j * 16 + l15;
#pragma unroll
      for (int r = 0; r < 4; r++) {
        const int row = m0 + quad * 4 + r;
        V[(size_t)row * DD + col] = __float2bfloat16(acc[j][r] + bsv[j]);
      }
    }
  }
}

// ---------------------------------------------------------------------------
// MFMA GEMM (bf16 A via global_load_lds): C = act(A @ W^T + bias (+res))
// BM=BN=128, BK=32, 4 waves, 4x4 16x16x32 tiles per wave.
// ---------------------------------------------------------------------------
template <int RELU, int ADD_RES, int BF16_OUT>
__global__ __launch_bounds__(256) void gemm_mfma(
    const bf16_t* __restrict__ A, const bf16_t* __restrict__ Wt,
    const float* __restrict__ bias, const float* __restrict__ res,
    void* __restrict__ Cout, int M, int N, int K) {
  __shared__ bf16_t As[128][32];
  __shared__ bf16_t Bs[128][32];
  const int tid = threadIdx.x;
  const int bn = blockIdx.x * 128;
  const int bm = blockIdx.y * 128;
  const int wave = tid >> 6;
  const int lane = tid & 63;
  const int l15 = lane & 15;
  const int quad = lane >> 4;
  const int wm = (wave & 1) * 64;
  const int wn = (wave >> 1) * 64;

  f32x4 acc[4][4];
#pragma unroll
  for (int i = 0; i < 4; i++)
#pragma unroll
    for (int j = 0; j < 4; j++) acc[i][j] = (f32x4){0.f, 0.f, 0.f, 0.f};

  const int srow = tid >> 2;
  const int skq = (tid & 3) * 8;

  for (int k0 = 0; k0 < K; k0 += 32) {
#pragma unroll
    for (int c = 0; c < 2; c++) {
      const int row = c * 64 + srow;
      const bf16_t* gp = A + (long)(bm + row) * K + k0 + skq;
      bf16_t* lp = &As[0][0] + (c * 2048 + wave * 512);
      __builtin_amdgcn_global_load_lds(
          (const __attribute__((address_space(1))) void*)gp,
          (__attribute__((address_space(3))) void*)lp, 16, 0, 0);
    }
#pragma unroll
    for (int c = 0; c < 2; c++) {
      const int row = c * 64 + srow;
      int wrow = bn + row;
      if (wrow >= N) wrow = N - 1;
      const bf16_t* gp = Wt + (long)wrow * K + k0 + skq;
      bf16_t* lp = &Bs[0][0] + (c * 2048 + wave * 512);
      __builtin_amdgcn_global_load_lds(
          (const __attribute__((address_space(1))) void*)gp,
          (__attribute__((address_space(3))) void*)lp, 16, 0, 0);
    }
    __syncthreads();
    bf16x8 af[4], bfr[4];
#pragma unroll
    for (int i = 0; i < 4; i++)
      af[i] = *(bf16x8*)&As[wm + i * 16 + l15][quad * 8];
#pragma unroll
    for (int j = 0; j < 4; j++)
      bfr[j] = *(bf16x8*)&Bs[wn + j * 16 + l15][quad * 8];
#pragma unroll
    for (int i = 0; i < 4; i++)
#pragma unroll
      for (int j = 0; j < 4; j++)
        acc[i][j] = __builtin_amdgcn_mfma_f32_16x16x32_bf16(af[i], bfr[j],
                                                            acc[i][j], 0, 0, 0);
    __syncthreads();
  }

  float bsv[4];
#pragma unroll
  for (int j = 0; j < 4; j++) {
    const int n = bn + wn + j * 16 + l15;
    bsv[j] = (n < N) ? bias[n] : 0.f;
  }
#pragma unroll
  for (int i = 0; i < 4; i++) {
#pragma unroll
    for (int r = 0; r < 4; r++) {
      const int m = bm + wm + i * 16 + quad * 4 + r;
#pragma unroll
      for (int j = 0; j < 4; j++) {
        const int n = bn + wn + j * 16 + l15;
        if (n < N) {
          float v = acc[i][j][r] + bsv[j];
          if (ADD_RES) v += res[(long)m * N + n];
          if (RELU) v = fmaxf(v, 0.f);
          if (BF16_OUT)
            ((__hip_bfloat16*)Cout)[(long)m * N + n] = __float2bfloat16(v);
          else
            ((float*)Cout)[(long)m * N + n] = v;
        }
      }
    }
  }
}

// ---------------------------------------------------------------------------
struct CastArgs {
  const float* src[8];
  __hip_bfloat16* dst[8];
  int len[8];
};
__global__ __launch_bounds__(256) void cast_weights(CastArgs a) {
  const int seg = blockIdx.y;
  const int base = blockIdx.x * 1024 + threadIdx.x * 4;
  if (base >= a.len[seg]) return;
  const float4 v = *(const float4*)(a.src[seg] + base);
  __hip_bfloat16* d = a.dst[seg] + base;
  d[0] = __float2bfloat16(v.x);
  d[1] = __float2bfloat16(v.y);
  d[2] = __float2bfloat16(v.z);
  d[3] = __float2bfloat16(v.w);
}

// ---------------------------------------------------------------------------
__global__ __launch_bounds__(256) void qp1_kernel(
    const float* __restrict__ rw, const float* __restrict__ Wp1,
    const float* __restrict__ bp1, __hip_bfloat16* __restrict__ out) {
  const int m = blockIdx.x;
  const int d = threadIdx.x;
  __shared__ float r[8];
  if (d < 8) r[d] = rw[m * 8 + d];
  __syncthreads();
  float s = bp1[d];
#pragma unroll
  for (int j = 0; j < 8; j++) s += r[j] * Wp1[d * 8 + j];
  out[(long)m * DD + d] = __float2bfloat16(fmaxf(s, 0.f));
}

// ---------------------------------------------------------------------------
__global__ __launch_bounds__(256) void attn_loc_kernel(
    const float* __restrict__ logits, const float* __restrict__ offp,
    const float* __restrict__ rw, float* __restrict__ attn,
    float* __restrict__ loc) {
  const int m = blockIdx.x;
  const int t = threadIdx.x;
  __shared__ float sl[200];
  __shared__ float soff[40];
  __shared__ float srw[8];
  if (t < 200) sl[t] = logits[(long)m * 200 + t];
  if (t >= 208 && t < 248) soff[t - 208] = offp[(long)m * 40 + (t - 208)];
  if (t >= 200 && t < 208) srw[t - 200] = rw[(long)m * 8 + (t - 200)];
  __syncthreads();
  if (t < 8) {
    float mx = -1e30f;
    for (int p = 0; p < 25; p++) mx = fmaxf(mx, sl[t * 25 + p]);
    float s = 0.f;
    for (int p = 0; p < 25; p++) s += __expf(sl[t * 25 + p] - mx);
    const float inv = 1.f / s;
    for (int p = 0; p < 25; p++)
      attn[(long)m * 200 + t * 25 + p] = __expf(sl[t * 25 + p] - mx) * inv;
  }
  if (t < 200) {
    const int h = t / 25;
    const int p = t - h * 25;
    const float cx = srw[0], cy = srw[1], w0 = srw[3], h0 = srw[4],
                ra = srw[6];
    const float ob0 = soff[h * 5 + 0], ob1 = soff[h * 5 + 1],
                ob2 = soff[h * 5 + 2], ob3 = soff[h * 5 + 3],
                oa = soff[h * 5 + 4];
    const float ang = (ra + oa * (1.f / 16.f)) * 6.28318530717958647692f;
    const float bx = cx + ob0 * 0.125f * w0;
    const float by = cy + ob1 * 0.125f * h0;
    const float bw = fmaxf(w0 + ob2 * 0.125f * w0, 0.f);
    const float bh = fmaxf(h0 + ob3 * 0.125f * h0, 0.f);
    const float gx = (float)((p % 5) - 2) * 0.2f * bw;
    const float gy = (float)((p / 5) - 2) * 0.2f * bh;
    float sn, cs;
    __sincosf(ang, &sn, &cs);
    loc[((long)m * 200 + t) * 2 + 0] = bx + cs * gx - sn * gy;
    loc[((long)m * 200 + t) * 2 + 1] = by + sn * gx + cs * gy;
  }
}

// ---------------------------------------------------------------------------
// Bilinear gather: lane = (h:3)(tap:2)(chunk:3); 4 channels per lane (bf16x4
// loads), taps reduced via shfl_xor(8,16). out bf16 (NQ,256).
// ---------------------------------------------------------------------------
__global__ __launch_bounds__(256) void sample_kernel(
    const bf16_t* __restrict__ v, const float* __restrict__ attn,
    const float* __restrict__ loc, bf16_t* __restrict__ out) {
  const int m = blockIdx.x;
  const int t = threadIdx.x;
  const int h = t >> 5;
  const int sub = t & 31;
  const int tap = sub >> 3;       // lane bits 3,4
  const int ch4 = (sub & 7) * 4;  // 4-channel chunk
  const float fdx = (float)(tap & 1);
  const float fdy = (float)(tap >> 1);
  __shared__ float sat[200];
  __shared__ float slc[400];
  if (t < 200) sat[t] = attn[(long)m * 200 + t];
  slc[t] = loc[(long)m * 400 + t];
  if (t < 144) slc[256 + t] = loc[(long)m * 400 + 256 + t];
  __syncthreads();
  float a0 = 0.f, a1 = 0.f, a2 = 0.f, a3 = 0.f;
  const bf16_t* vb = v + h * HDD + ch4;
  for (int p = 0; p < 25; p++) {
    const float lx = slc[(h * 25 + p) * 2 + 0];
    const float ly = slc[(h * 25 + p) * 2 + 1];
    const float aw = sat[h * 25 + p];
    const float x = lx * (float)WW - 0.5f;
    const float y = ly * (float)HH - 0.5f;
    const float x0 = floorf(x);
    const float y0 = floorf(y);
    const float xi = x0 + fdx;
    const float yi = y0 + fdy;
    const float wgt = (1.f - fabsf(x - xi)) * (1.f - fabsf(y - yi));
    const bool valid = (xi >= 0.f) && (xi <= (float)(WW - 1)) &&
                       (yi >= 0.f) && (yi <= (float)(HH - 1));
    const int xc = (int)fminf(fmaxf(xi, 0.f), (float)(WW - 1));
    const int yc = (int)fminf(fmaxf(yi, 0.f), (float)(HH - 1));
    const int idx = yc * WW + xc;
    const bf16x4 g = *(const bf16x4*)(vb + (size_t)idx * DD);
    const float wv = valid ? aw * wgt : 0.f;
    a0 += wv * (float)g[0];
    a1 += wv * (float)g[1];
    a2 += wv * (float)g[2];
    a3 += wv * (float)g[3];
  }
  // reduce over tap lanes (xor bits 3,4 — h bit (5) untouched)
  a0 += __shfl_xor(a0, 8);  a1 += __shfl_xor(a1, 8);
  a2 += __shfl_xor(a2, 8);  a3 += __shfl_xor(a3, 8);
  a0 += __shfl_xor(a0, 16); a1 += __shfl_xor(a1, 16);
  a2 += __shfl_xor(a2, 16); a3 += __shfl_xor(a3, 16);
  if (tap == 0) {
    bf16x4 o;
    o[0] = (bf16_t)a0; o[1] = (bf16_t)a1; o[2] = (bf16_t)a2; o[3] = (bf16_t)a3;
    *(bf16x4*)(out + (size_t)m * DD + h * HDD + ch4) = o;
  }
}

// ---------------------------------------------------------------------------
__global__ __launch_bounds__(256) void ln_kernel(
    const float* __restrict__ x, const float* __restrict__ resid,
    const float* __restrict__ g, const float* __restrict__ b,
    float* __restrict__ out, __hip_bfloat16* __restrict__ out_bf) {
  const int m = blockIdx.x;
  const int d = threadIdx.x;
  const float v = x[(long)m * DD + d] + resid[(long)m * DD + d];
  __shared__ float red[256];
  __shared__ float mean_s, inv_s;
  red[d] = v;
  __syncthreads();
  for (int s = 128; s > 0; s >>= 1) {
    if (d < s) red[d] += red[d + s];
    __syncthreads();
  }
  if (d == 0) mean_s = red[0] * (1.f / 256.f);
  __syncthreads();
  const float mu = mean_s;
  const float diff = v - mu;
  red[d] = diff * diff;
  __syncthreads();
  for (int s = 128; s > 0; s >>= 1) {
    if (d < s) red[d] += red[d + s];
    __syncthreads();
  }
  if (d == 0) inv_s = rsqrtf(red[0] * (1.f / 256.f) + 1e-5f);
  __syncthreads();
  const float o = diff * inv_s * g[d] + b[d];
  out[(long)m * DD + d] = o;
  if (out_bf) out_bf[(long)m * DD + d] = __float2bfloat16(o);
}

// ---------------------------------------------------------------------------
extern "C" void kernel_launch(void* const* d_in, const int* in_sizes, int n_in,
                              void* d_out, int out_size, void* d_ws,
                              size_t ws_size, hipStream_t stream) {
  const float* query = (const float*)d_in[0];
  const float* memory = (const float*)d_in[1];
  const float* rw = (const float*)d_in[2];
  const float* Wp1 = (const float*)d_in[5];
  const float* bp1 = (const float*)d_in[6];
  const float* Wp2 = (const float*)d_in[7];
  const float* bp2 = (const float*)d_in[8];
  const float* Wp3 = (const float*)d_in[9];
  const float* bp3 = (const float*)d_in[10];
  const float* Wv = (const float*)d_in[11];
  const float* bv = (const float*)d_in[12];
  const float* Wa = (const float*)d_in[13];
  const float* ba = (const float*)d_in[14];
  const float* Wb = (const float*)d_in[15];
  const float* bb = (const float*)d_in[16];
  const float* Wo = (const float*)d_in[17];
  const float* bo = (const float*)d_in[18];
  const float* W1 = (const float*)d_in[19];
  const float* b1 = (const float*)d_in[20];
  const float* W2 = (const float*)d_in[21];
  const float* b2 = (const float*)d_in[22];
  const float* g2 = (const float*)d_in[23];
  const float* be2 = (const float*)d_in[24];
  const float* g3 = (const float*)d_in[25];
  const float* be3 = (const float*)d_in[26];

  char* ws = (char*)d_ws;
  size_t off = 0;
  auto alloc = [&](size_t bytes) {
    void* p = ws + off;
    off += (bytes + 255) & ~(size_t)255;
    return p;
  };
  __hip_bfloat16* vbuf = (__hip_bfloat16*)alloc((size_t)HWSZ * DD * 2); // 134MB
  __hip_bfloat16* qp1bf = (__hip_bfloat16*)alloc((size_t)NQ * DD * 2);
  __hip_bfloat16* qp2bf = (__hip_bfloat16*)alloc((size_t)NQ * DD * 2);
  __hip_bfloat16* qbf = (__hip_bfloat16*)alloc((size_t)NQ * DD * 2);
  __hip_bfloat16* oabf = (__hip_bfloat16*)alloc((size_t)NQ * DD * 2);
  __hip_bfloat16* xqbf = (__hip_bfloat16*)alloc((size_t)NQ * DD * 2);
  __hip_bfloat16* h1bf = (__hip_bfloat16*)alloc((size_t)NQ * DFF * 2);
  float* xq32 = (float*)alloc((size_t)NQ * DD * 4);
  float* f32buf = (float*)alloc((size_t)NQ * DD * 4);
  float* offbuf = (float*)alloc((size_t)NQ * 40 * 4);
  float* attnbuf = (float*)alloc((size_t)NQ * 200 * 4);
  float* locbuf = (float*)alloc((size_t)NQ * 200 * 2 * 4);
  __hip_bfloat16* Wp2b = (__hip_bfloat16*)alloc(65536 * 2);
  __hip_bfloat16* Wp3b = (__hip_bfloat16*)alloc(65536 * 2);
  __hip_bfloat16* Wvb = (__hip_bfloat16*)alloc(65536 * 2);
  __hip_bfloat16* Wab = (__hip_bfloat16*)alloc(51200 * 2);
  __hip_bfloat16* Wbb = (__hip_bfloat16*)alloc(10240 * 2);
  __hip_bfloat16* Wob = (__hip_bfloat16*)alloc(65536 * 2);
  __hip_bfloat16* W1b = (__hip_bfloat16*)alloc(262144 * 2);
  __hip_bfloat16* W2b = (__hip_bfloat16*)alloc(262144 * 2);
  (void)ws_size;

  CastArgs ca;
  ca.src[0] = Wp2; ca.dst[0] = Wp2b; ca.len[0] = 65536;
  ca.src[1] = Wp3; ca.dst[1] = Wp3b; ca.len[1] = 65536;
  ca.src[2] = Wv;  ca.dst[2] = Wvb;  ca.len[2] = 65536;
  ca.src[3] = Wa;  ca.dst[3] = Wab;  ca.len[3] = 51200;
  ca.src[4] = Wb;  ca.dst[4] = Wbb;  ca.len[4] = 10240;
  ca.src[5] = Wo;  ca.dst[5] = Wob;  ca.len[5] = 65536;
  ca.src[6] = W1;  ca.dst[6] = W1b;  ca.len[6] = 262144;
  ca.src[7] = W2;  ca.dst[7] = W2b;  ca.len[7] = 262144;
  cast_weights<<<dim3(256, 8), 256, 0, stream>>>(ca);

  qp1_kernel<<<NQ, 256, 0, stream>>>(rw, Wp1, bp1, qp1bf);
  gemm_mfma<1, 0, 1><<<dim3(2, NQ / 128), 256, 0, stream>>>(
      (const bf16_t*)qp1bf, (const bf16_t*)Wp2b, bp2, nullptr, qp2bf, NQ, DD,
      DD);
  gemm_mfma<0, 1, 1><<<dim3(2, NQ / 128), 256, 0, stream>>>(
      (const bf16_t*)qp2bf, (const bf16_t*)Wp3b, bp3, query, qbf, NQ, DD, DD);
  // v = memory @ Wv^T + bv : barrier-free streaming kernel
  wv_kernel<<<HWSZ / 256, 256, 0, stream>>>(memory, (const bf16_t*)Wvb, bv,
                                            vbuf);
  gemm_mfma<0, 0, 0><<<dim3(2, NQ / 128), 256, 0, stream>>>(
      (const bf16_t*)qbf, (const bf16_t*)Wab, ba, nullptr, f32buf, NQ, 200,
      DD);
  gemm_mfma<0, 0, 0><<<dim3(1, NQ / 128), 256, 0, stream>>>(
      (const bf16_t*)qbf, (const bf16_t*)Wbb, bb, nullptr, offbuf, NQ, 40, DD);
  attn_loc_kernel<<<NQ, 256, 0, stream>>>(f32buf, offbuf, rw, attnbuf, locbuf);
  sample_kernel<<<NQ, 256, 0, stream>>>((const bf16_t*)vbuf, attnbuf, locbuf,
                                        (bf16_t*)oabf);
  gemm_mfma<0, 0, 0><<<dim3(2, NQ / 128), 256, 0, stream>>>(
      (const bf16_t*)oabf, (const bf16_t*)Wob, bo, nullptr, f32buf, NQ, DD,
      DD);
  ln_kernel<<<NQ, 256, 0, stream>>>(f32buf, query, g2, be2, xq32, xqbf);
  gemm_mfma<1, 0, 1><<<dim3(8, NQ / 128), 256, 0, stream>>>(
      (const bf16_t*)xqbf, (const bf16_t*)W1b, b1, nullptr, h1bf, NQ, DFF, DD);
  gemm_mfma<0, 0, 0><<<dim3(2, NQ / 128), 256, 0, stream>>>(
      (const bf16_t*)h1bf, (const bf16_t*)W2b, b2, nullptr, f32buf, NQ, DD,
      DFF);
  ln_kernel<<<NQ, 256, 0, stream>>>(f32buf, xq32, g3, be3, (float*)d_out,
                                    nullptr);
}

// Round 4
// 770.591 us; speedup vs baseline: 1.0714x; 1.0714x over previous
//
#include <hip/hip_runtime.h>
#include <hip/hip_bf16.h>
#include <math.h>

#define NQ 8192
#define DD 256
#define NHD 8
#define HDD 32
#define PP 25
#define HH 512
#define WW 512
#define HWSZ (HH * WW)
#define DFF 1024

typedef __bf16 bf16_t;
typedef bf16_t bf16x8 __attribute__((ext_vector_type(8)));
typedef bf16_t bf16x4 __attribute__((ext_vector_type(4)));
typedef float f32x4 __attribute__((ext_vector_type(4)));

// ---------------------------------------------------------------------------
// Wv projection: V(HW,256) = bf16( memory(HW,256)fp32 @ Wv^T + bv )
// Block: 256 rows x 64-col n-slice. W-slice (64x256 bf16 = 32KB, padded
// stride 264, col-interleaved rows) staged to LDS ONCE; then a BARRIER-FREE
// K-loop: A frags global->VGPR direct (lane m=l15, k=quad*8: two float4,
// cvt inline), B frags ds_read_b128. Stores packed bf16x4 (j-interleaved).
// ---------------------------------------------------------------------------
__global__ __launch_bounds__(256) void wv_kernel(
    const float* __restrict__ A, const bf16_t* __restrict__ Wt,
    const float* __restrict__ bias, bf16_t* __restrict__ V) {
  __shared__ bf16_t Bs[64][264];  // stride 264: b128-aligned, 2-way banks
  const int tid = threadIdx.x;
  const int wave = tid >> 6;
  const int lane = tid & 63;
  const int l15 = lane & 15;
  const int quad = lane >> 4;
  const int nbase = (blockIdx.x & 3) * 64;
  const int mbase = (blockIdx.x >> 2) * 256;

  // Stage B once. Row rr holds W row nbase + swz(rr), swz(rr)=(rr&15)*4+(rr>>4)
  // so that frag tile j, lane l15 (Bs[j*16+l15]) = W row l15*4+j (col-interleave).
  {
    const int rr = tid & 63;
    const int seg = tid >> 6;  // 4 segments x 64 elements
    const int wrow = nbase + ((rr & 15) * 4 + (rr >> 4));
    const bf16_t* gp = Wt + (size_t)wrow * 256 + seg * 64;
#pragma unroll
    for (int u = 0; u < 8; u++)
      *(bf16x8*)&Bs[rr][seg * 64 + u * 8] = *(const bf16x8*)(gp + u * 8);
  }
  __syncthreads();

  const int m0 = mbase + wave * 64;  // wave owns 64 rows x 64 cols
  f32x4 acc[4][4];
#pragma unroll
  for (int i = 0; i < 4; i++)
#pragma unroll
    for (int j = 0; j < 4; j++) acc[i][j] = (f32x4){0.f, 0.f, 0.f, 0.f};
  float bsv[4];
#pragma unroll
  for (int j = 0; j < 4; j++) bsv[j] = bias[nbase + l15 * 4 + j];

#pragma unroll
  for (int kt = 0; kt < 8; kt++) {
    const int k0 = kt * 32;
    bf16x8 afr[4];
#pragma unroll
    for (int i = 0; i < 4; i++) {
      const float* ap = A + (size_t)(m0 + i * 16 + l15) * 256 + k0 + quad * 8;
      const float4 a0 = *(const float4*)ap;
      const float4 a1 = *(const float4*)(ap + 4);
      afr[i][0] = (bf16_t)a0.x; afr[i][1] = (bf16_t)a0.y;
      afr[i][2] = (bf16_t)a0.z; afr[i][3] = (bf16_t)a0.w;
      afr[i][4] = (bf16_t)a1.x; afr[i][5] = (bf16_t)a1.y;
      afr[i][6] = (bf16_t)a1.z; afr[i][7] = (bf16_t)a1.w;
    }
#pragma unroll
    for (int j = 0; j < 4; j++) {
      const bf16x8 bfr = *(const bf16x8*)&Bs[j * 16 + l15][k0 + quad * 8];
#pragma unroll
      for (int i = 0; i < 4; i++)
        acc[i][j] = __builtin_amdgcn_mfma_f32_16x16x32_bf16(afr[i], bfr,
                                                            acc[i][j], 0, 0, 0);
    }
  }

  // store: row = m0+i*16+quad*4+r, cols nbase+l15*4 .. +4 (j-packed, 8B)
#pragma unroll
  for (int i = 0; i < 4; i++) {
#pragma unroll
    for (int r = 0; r < 4; r++) {
      const int row = m0 + i * 16 + quad * 4 + r;
      bf16x4 o;
#pragma unroll
      for (int j = 0; j < 4; j++) o[j] = (bf16_t)(acc[i][j][r] + bsv[j]);
      *(bf16x4*)(V + (size_t)row * DD + nbase + l15 * 4) = o;
    }
  }
}

// ---------------------------------------------------------------------------
// MFMA GEMM (bf16 A via global_load_lds): C = act(A @ W^T + bias (+res))
// BM=BN=128, BK=32, 4 waves, 4x4 16x16x32 tiles per wave. Split-bias via
// (bias2, split) for concatenated weight matrices.
// ---------------------------------------------------------------------------
template <int RELU, int ADD_RES, int BF16_OUT>
__global__ __launch_bounds__(256) void gemm_mfma(
    const bf16_t* __restrict__ A, const bf16_t* __restrict__ Wt,
    const float* __restrict__ bias, const float* __restrict__ bias2, int split,
    const float* __restrict__ res, void* __restrict__ Cout, int M, int N,
    int K) {
  __shared__ bf16_t As[128][32];
  __shared__ bf16_t Bs[128][32];
  const int tid = threadIdx.x;
  const int bn = blockIdx.x * 128;
  const int bm = blockIdx.y * 128;
  const int wave = tid >> 6;
  const int lane = tid & 63;
  const int l15 = lane & 15;
  const int quad = lane >> 4;
  const int wm = (wave & 1) * 64;
  const int wn = (wave >> 1) * 64;

  f32x4 acc[4][4];
#pragma unroll
  for (int i = 0; i < 4; i++)
#pragma unroll
    for (int j = 0; j < 4; j++) acc[i][j] = (f32x4){0.f, 0.f, 0.f, 0.f};

  const int srow = tid >> 2;
  const int skq = (tid & 3) * 8;

  for (int k0 = 0; k0 < K; k0 += 32) {
#pragma unroll
    for (int c = 0; c < 2; c++) {
      const int row = c * 64 + srow;
      const bf16_t* gp = A + (long)(bm + row) * K + k0 + skq;
      bf16_t* lp = &As[0][0] + (c * 2048 + wave * 512);
      __builtin_amdgcn_global_load_lds(
          (const __attribute__((address_space(1))) void*)gp,
          (__attribute__((address_space(3))) void*)lp, 16, 0, 0);
    }
#pragma unroll
    for (int c = 0; c < 2; c++) {
      const int row = c * 64 + srow;
      int wrow = bn + row;
      if (wrow >= N) wrow = N - 1;
      const bf16_t* gp = Wt + (long)wrow * K + k0 + skq;
      bf16_t* lp = &Bs[0][0] + (c * 2048 + wave * 512);
      __builtin_amdgcn_global_load_lds(
          (const __attribute__((address_space(1))) void*)gp,
          (__attribute__((address_space(3))) void*)lp, 16, 0, 0);
    }
    __syncthreads();
    bf16x8 af[4], bfr[4];
#pragma unroll
    for (int i = 0; i < 4; i++)
      af[i] = *(bf16x8*)&As[wm + i * 16 + l15][quad * 8];
#pragma unroll
    for (int j = 0; j < 4; j++)
      bfr[j] = *(bf16x8*)&Bs[wn + j * 16 + l15][quad * 8];
#pragma unroll
    for (int i = 0; i < 4; i++)
#pragma unroll
      for (int j = 0; j < 4; j++)
        acc[i][j] = __builtin_amdgcn_mfma_f32_16x16x32_bf16(af[i], bfr[j],
                                                            acc[i][j], 0, 0, 0);
    __syncthreads();
  }

  float bsv[4];
#pragma unroll
  for (int j = 0; j < 4; j++) {
    const int n = bn + wn + j * 16 + l15;
    bsv[j] = (n >= N) ? 0.f : (n < split ? bias[n] : bias2[n - split]);
  }
#pragma unroll
  for (int i = 0; i < 4; i++) {
#pragma unroll
    for (int r = 0; r < 4; r++) {
      const int m = bm + wm + i * 16 + quad * 4 + r;
#pragma unroll
      for (int j = 0; j < 4; j++) {
        const int n = bn + wn + j * 16 + l15;
        if (n < N) {
          float v = acc[i][j][r] + bsv[j];
          if (ADD_RES) v += res[(long)m * N + n];
          if (RELU) v = fmaxf(v, 0.f);
          if (BF16_OUT)
            ((__hip_bfloat16*)Cout)[(long)m * N + n] = __float2bfloat16(v);
          else
            ((float*)Cout)[(long)m * N + n] = v;
        }
      }
    }
  }
}

// ---------------------------------------------------------------------------
struct CastArgs {
  const float* src[8];
  __hip_bfloat16* dst[8];
  int len[8];
};
__global__ __launch_bounds__(256) void cast_weights(CastArgs a) {
  const int seg = blockIdx.y;
  const int base = blockIdx.x * 1024 + threadIdx.x * 4;
  if (base >= a.len[seg]) return;
  const float4 v = *(const float4*)(a.src[seg] + base);
  __hip_bfloat16* d = a.dst[seg] + base;
  d[0] = __float2bfloat16(v.x);
  d[1] = __float2bfloat16(v.y);
  d[2] = __float2bfloat16(v.z);
  d[3] = __float2bfloat16(v.w);
}

// ---------------------------------------------------------------------------
__global__ __launch_bounds__(256) void qp1_kernel(
    const float* __restrict__ rw, const float* __restrict__ Wp1,
    const float* __restrict__ bp1, __hip_bfloat16* __restrict__ out) {
  const int m = blockIdx.x;
  const int d = threadIdx.x;
  __shared__ float r[8];
  if (d < 8) r[d] = rw[m * 8 + d];
  __syncthreads();
  float s = bp1[d];
#pragma unroll
  for (int j = 0; j < 8; j++) s += r[j] * Wp1[d * 8 + j];
  out[(long)m * DD + d] = __float2bfloat16(fmaxf(s, 0.f));
}

// ---------------------------------------------------------------------------
// Fused: softmax + location decode + bilinear gather + attn-weighted sum.
// lg: (NQ,240) = [logits(200) | off(40)]. lane = (h:3)(tap:2)(chunk:3).
// ---------------------------------------------------------------------------
__global__ __launch_bounds__(256) void sample_kernel(
    const bf16_t* __restrict__ v, const float* __restrict__ lg,
    const float* __restrict__ rw, bf16_t* __restrict__ out) {
  const int m = blockIdx.x;
  const int t = threadIdx.x;
  const int h = t >> 5;
  const int sub = t & 31;
  const int tap = sub >> 3;
  const int ch4 = (sub & 7) * 4;
  const float fdx = (float)(tap & 1);
  const float fdy = (float)(tap >> 1);
  __shared__ float sl[240];   // logits | off
  __shared__ float srw[8];
  __shared__ float sat[200];
  __shared__ float slc[400];
  if (t < 240) sl[t] = lg[(long)m * 240 + t];
  if (t >= 240 && t < 248) srw[t - 240] = rw[(long)m * 8 + (t - 240)];
  __syncthreads();
  if (t < 8) {
    float mx = -1e30f;
    for (int p = 0; p < 25; p++) mx = fmaxf(mx, sl[t * 25 + p]);
    float s = 0.f;
    for (int p = 0; p < 25; p++) s += __expf(sl[t * 25 + p] - mx);
    const float inv = 1.f / s;
    for (int p = 0; p < 25; p++)
      sat[t * 25 + p] = __expf(sl[t * 25 + p] - mx) * inv;
  }
  if (t < 200) {
    const int hh = t / 25;
    const int p = t - hh * 25;
    const float cx = srw[0], cy = srw[1], w0 = srw[3], h0 = srw[4],
                ra = srw[6];
    const float* o5 = &sl[200 + hh * 5];
    const float ang = (ra + o5[4] * (1.f / 16.f)) * 6.28318530717958647692f;
    const float bx = cx + o5[0] * 0.125f * w0;
    const float by = cy + o5[1] * 0.125f * h0;
    const float bw = fmaxf(w0 + o5[2] * 0.125f * w0, 0.f);
    const float bh = fmaxf(h0 + o5[3] * 0.125f * h0, 0.f);
    const float gx = (float)((p % 5) - 2) * 0.2f * bw;
    const float gy = (float)((p / 5) - 2) * 0.2f * bh;
    float sn, cs;
    __sincosf(ang, &sn, &cs);
    slc[t * 2 + 0] = bx + cs * gx - sn * gy;
    slc[t * 2 + 1] = by + sn * gx + cs * gy;
  }
  __syncthreads();
  float a0 = 0.f, a1 = 0.f, a2 = 0.f, a3 = 0.f;
  const bf16_t* vb = v + h * HDD + ch4;
  for (int p = 0; p < 25; p++) {
    const float lx = slc[(h * 25 + p) * 2 + 0];
    const float ly = slc[(h * 25 + p) * 2 + 1];
    const float aw = sat[h * 25 + p];
    const float x = lx * (float)WW - 0.5f;
    const float y = ly * (float)HH - 0.5f;
    const float x0 = floorf(x);
    const float y0 = floorf(y);
    const float xi = x0 + fdx;
    const float yi = y0 + fdy;
    const float wgt = (1.f - fabsf(x - xi)) * (1.f - fabsf(y - yi));
    const bool valid = (xi >= 0.f) && (xi <= (float)(WW - 1)) &&
                       (yi >= 0.f) && (yi <= (float)(HH - 1));
    const int xc = (int)fminf(fmaxf(xi, 0.f), (float)(WW - 1));
    const int yc = (int)fminf(fmaxf(yi, 0.f), (float)(HH - 1));
    const int idx = yc * WW + xc;
    const bf16x4 g = *(const bf16x4*)(vb + (size_t)idx * DD);
    const float wv = valid ? aw * wgt : 0.f;
    a0 += wv * (float)g[0];
    a1 += wv * (float)g[1];
    a2 += wv * (float)g[2];
    a3 += wv * (float)g[3];
  }
  a0 += __shfl_xor(a0, 8);  a1 += __shfl_xor(a1, 8);
  a2 += __shfl_xor(a2, 8);  a3 += __shfl_xor(a3, 8);
  a0 += __shfl_xor(a0, 16); a1 += __shfl_xor(a1, 16);
  a2 += __shfl_xor(a2, 16); a3 += __shfl_xor(a3, 16);
  if (tap == 0) {
    bf16x4 o;
    o[0] = (bf16_t)a0; o[1] = (bf16_t)a1; o[2] = (bf16_t)a2; o[3] = (bf16_t)a3;
    *(bf16x4*)(out + (size_t)m * DD + h * HDD + ch4) = o;
  }
}

// ---------------------------------------------------------------------------
__global__ __launch_bounds__(256) void ln_kernel(
    const float* __restrict__ x, const float* __restrict__ resid,
    const float* __restrict__ g, const float* __restrict__ b,
    float* __restrict__ out, __hip_bfloat16* __restrict__ out_bf) {
  const int m = blockIdx.x;
  const int d = threadIdx.x;
  const float v = x[(long)m * DD + d] + resid[(long)m * DD + d];
  __shared__ float red[256];
  __shared__ float mean_s, inv_s;
  red[d] = v;
  __syncthreads();
  for (int s = 128; s > 0; s >>= 1) {
    if (d < s) red[d] += red[d + s];
    __syncthreads();
  }
  if (d == 0) mean_s = red[0] * (1.f / 256.f);
  __syncthreads();
  const float mu = mean_s;
  const float diff = v - mu;
  red[d] = diff * diff;
  __syncthreads();
  for (int s = 128; s > 0; s >>= 1) {
    if (d < s) red[d] += red[d + s];
    __syncthreads();
  }
  if (d == 0) inv_s = rsqrtf(red[0] * (1.f / 256.f) + 1e-5f);
  __syncthreads();
  const float o = diff * inv_s * g[d] + b[d];
  out[(long)m * DD + d] = o;
  if (out_bf) out_bf[(long)m * DD + d] = __float2bfloat16(o);
}

// ---------------------------------------------------------------------------
extern "C" void kernel_launch(void* const* d_in, const int* in_sizes, int n_in,
                              void* d_out, int out_size, void* d_ws,
                              size_t ws_size, hipStream_t stream) {
  const float* query = (const float*)d_in[0];
  const float* memory = (const float*)d_in[1];
  const float* rw = (const float*)d_in[2];
  const float* Wp1 = (const float*)d_in[5];
  const float* bp1 = (const float*)d_in[6];
  const float* Wp2 = (const float*)d_in[7];
  const float* bp2 = (const float*)d_in[8];
  const float* Wp3 = (const float*)d_in[9];
  const float* bp3 = (const float*)d_in[10];
  const float* Wv = (const float*)d_in[11];
  const float* bv = (const float*)d_in[12];
  const float* Wa = (const float*)d_in[13];
  const float* ba = (const float*)d_in[14];
  const float* Wb = (const float*)d_in[15];
  const float* bb = (const float*)d_in[16];
  const float* Wo = (const float*)d_in[17];
  const float* bo = (const float*)d_in[18];
  const float* W1 = (const float*)d_in[19];
  const float* b1 = (const float*)d_in[20];
  const float* W2 = (const float*)d_in[21];
  const float* b2 = (const float*)d_in[22];
  const float* g2 = (const float*)d_in[23];
  const float* be2 = (const float*)d_in[24];
  const float* g3 = (const float*)d_in[25];
  const float* be3 = (const float*)d_in[26];

  char* ws = (char*)d_ws;
  size_t off = 0;
  auto alloc = [&](size_t bytes) {
    void* p = ws + off;
    off += (bytes + 255) & ~(size_t)255;
    return p;
  };
  __hip_bfloat16* vbuf = (__hip_bfloat16*)alloc((size_t)HWSZ * DD * 2); // 134MB
  __hip_bfloat16* qp1bf = (__hip_bfloat16*)alloc((size_t)NQ * DD * 2);
  __hip_bfloat16* qp2bf = (__hip_bfloat16*)alloc((size_t)NQ * DD * 2);
  __hip_bfloat16* qbf = (__hip_bfloat16*)alloc((size_t)NQ * DD * 2);
  __hip_bfloat16* oabf = (__hip_bfloat16*)alloc((size_t)NQ * DD * 2);
  __hip_bfloat16* xqbf = (__hip_bfloat16*)alloc((size_t)NQ * DD * 2);
  __hip_bfloat16* h1bf = (__hip_bfloat16*)alloc((size_t)NQ * DFF * 2);
  float* xq32 = (float*)alloc((size_t)NQ * DD * 4);
  float* f32buf = (float*)alloc((size_t)NQ * DD * 4);   // q2 / f2
  float* lgbuf = (float*)alloc((size_t)NQ * 240 * 4);   // logits|off
  __hip_bfloat16* Wp2b = (__hip_bfloat16*)alloc(65536 * 2);
  __hip_bfloat16* Wp3b = (__hip_bfloat16*)alloc(65536 * 2);
  __hip_bfloat16* Wvb = (__hip_bfloat16*)alloc(65536 * 2);
  __hip_bfloat16* Wabb = (__hip_bfloat16*)alloc(61440 * 2);  // Wa|Wb concat
  __hip_bfloat16* Wob = (__hip_bfloat16*)alloc(65536 * 2);
  __hip_bfloat16* W1b = (__hip_bfloat16*)alloc(262144 * 2);
  __hip_bfloat16* W2b = (__hip_bfloat16*)alloc(262144 * 2);
  (void)ws_size;

  CastArgs ca;
  ca.src[0] = Wp2; ca.dst[0] = Wp2b;          ca.len[0] = 65536;
  ca.src[1] = Wp3; ca.dst[1] = Wp3b;          ca.len[1] = 65536;
  ca.src[2] = Wv;  ca.dst[2] = Wvb;           ca.len[2] = 65536;
  ca.src[3] = Wa;  ca.dst[3] = Wabb;          ca.len[3] = 51200;
  ca.src[4] = Wb;  ca.dst[4] = Wabb + 51200;  ca.len[4] = 10240;
  ca.src[5] = Wo;  ca.dst[5] = Wob;           ca.len[5] = 65536;
  ca.src[6] = W1;  ca.dst[6] = W1b;           ca.len[6] = 262144;
  ca.src[7] = W2;  ca.dst[7] = W2b;           ca.len[7] = 262144;
  cast_weights<<<dim3(256, 8), 256, 0, stream>>>(ca);

  qp1_kernel<<<NQ, 256, 0, stream>>>(rw, Wp1, bp1, qp1bf);
  gemm_mfma<1, 0, 1><<<dim3(2, NQ / 128), 256, 0, stream>>>(
      (const bf16_t*)qp1bf, (const bf16_t*)Wp2b, bp2, nullptr, 1 << 30,
      nullptr, qp2bf, NQ, DD, DD);
  gemm_mfma<0, 1, 1><<<dim3(2, NQ / 128), 256, 0, stream>>>(
      (const bf16_t*)qp2bf, (const bf16_t*)Wp3b, bp3, nullptr, 1 << 30, query,
      qbf, NQ, DD, DD);
  // v = memory @ Wv^T + bv : barrier-free K-loop, B-slice resident in LDS
  wv_kernel<<<(HWSZ / 256) * 4, 256, 0, stream>>>(memory, (const bf16_t*)Wvb,
                                                  bv, (bf16_t*)vbuf);
  // [logits | off] = q @ [Wa;Wb]^T + [ba;bb]  (N=240, split bias at 200)
  gemm_mfma<0, 0, 0><<<dim3(2, NQ / 128), 256, 0, stream>>>(
      (const bf16_t*)qbf, (const bf16_t*)Wabb, ba, bb, 200, nullptr, lgbuf,
      NQ, 240, DD);
  // fused softmax + loc decode + bilinear sample
  sample_kernel<<<NQ, 256, 0, stream>>>((const bf16_t*)vbuf, lgbuf, rw,
                                        (bf16_t*)oabf);
  gemm_mfma<0, 0, 0><<<dim3(2, NQ / 128), 256, 0, stream>>>(
      (const bf16_t*)oabf, (const bf16_t*)Wob, bo, nullptr, 1 << 30, nullptr,
      f32buf, NQ, DD, DD);
  ln_kernel<<<NQ, 256, 0, stream>>>(f32buf, query, g2, be2, xq32, xqbf);
  gemm_mfma<1, 0, 1><<<dim3(8, NQ / 128), 256, 0, stream>>>(
      (const bf16_t*)xqbf, (const bf16_t*)W1b, b1, nullptr, 1 << 30, nullptr,
      h1bf, NQ, DFF, DD);
  gemm_mfma<0, 0, 0><<<dim3(2, NQ / 128), 256, 0, stream>>>(
      (const bf16_t*)h1bf, (const bf16_t*)W2b, b2, nullptr, 1 << 30, nullptr,
      f32buf, NQ, DD, DFF);
  ln_kernel<<<NQ, 256, 0, stream>>>(f32buf, xq32, g3, be3, (float*)d_out,
                                    nullptr);
}